// Round 1
// baseline (89.599 us; speedup 1.0000x reference)
//
#include <hip/hip_runtime.h>
#include <math.h>

// SpikingNeuron forward scan.
// x: (N, T) f32 row-major; beta, threshold: scalars; init_rand: (N,) f32.
// out = [spikes (N*T) | mems (N*T)] f32.
//
// Forward-value semantics (stop_gradient collapses):
//   fb   = sigmoid(beta)
//   m    = init_rand * thr                      (recorded as mems[:,0] pre-step)
//   m_new = fb*m + x[:,t]        (mul then add, NO fma -- must match numpy f32)
//   surplus = m_new - thr
//   spike = (surplus >= 0) ? 1 : 0
//   m     = spike ? surplus : m_new   (surplus == m_new - 1.0f*thr, one rounding)

#define N_BATCH 65536
#define T_STEPS 256
#define T4 (T_STEPS / 4)

__global__ __launch_bounds__(256) void snn_fwd_kernel(
    const float* __restrict__ x,
    const float* __restrict__ beta_p,
    const float* __restrict__ thr_p,
    const float* __restrict__ init_rand,
    float* __restrict__ out)
{
#pragma clang fp contract(off)
    const int row = blockIdx.x * blockDim.x + threadIdx.x;
    if (row >= N_BATCH) return;

    const float thr = thr_p[0];
    // Correctly-rounded f32 sigmoid via double intermediate.
    const float fb = (float)(1.0 / (1.0 + exp(-(double)beta_p[0])));

    float m = init_rand[row] * thr;

    const float4* __restrict__ xr =
        reinterpret_cast<const float4*>(x) + (size_t)row * T4;
    float4* __restrict__ sr =
        reinterpret_cast<float4*>(out) + (size_t)row * T4;
    float4* __restrict__ mr =
        reinterpret_cast<float4*>(out + (size_t)N_BATCH * T_STEPS) + (size_t)row * T4;

#pragma unroll 4
    for (int i = 0; i < T4; ++i) {
        const float4 xv = xr[i];
        float4 sv, mv;

        {
            mv.x = m;
            float prod = fb * m;
            float mn   = prod + xv.x;
            float su   = mn - thr;
            float h    = (su >= 0.0f) ? 1.0f : 0.0f;
            sv.x = h;
            m = (su >= 0.0f) ? su : mn;
        }
        {
            mv.y = m;
            float prod = fb * m;
            float mn   = prod + xv.y;
            float su   = mn - thr;
            float h    = (su >= 0.0f) ? 1.0f : 0.0f;
            sv.y = h;
            m = (su >= 0.0f) ? su : mn;
        }
        {
            mv.z = m;
            float prod = fb * m;
            float mn   = prod + xv.z;
            float su   = mn - thr;
            float h    = (su >= 0.0f) ? 1.0f : 0.0f;
            sv.z = h;
            m = (su >= 0.0f) ? su : mn;
        }
        {
            mv.w = m;
            float prod = fb * m;
            float mn   = prod + xv.w;
            float su   = mn - thr;
            float h    = (su >= 0.0f) ? 1.0f : 0.0f;
            sv.w = h;
            m = (su >= 0.0f) ? su : mn;
        }

        sr[i] = sv;
        mr[i] = mv;
    }
}

extern "C" void kernel_launch(void* const* d_in, const int* in_sizes, int n_in,
                              void* d_out, int out_size, void* d_ws, size_t ws_size,
                              hipStream_t stream) {
    const float* x         = (const float*)d_in[0];
    const float* beta      = (const float*)d_in[1];
    const float* threshold = (const float*)d_in[2];
    const float* init_rand = (const float*)d_in[3];
    float* out             = (float*)d_out;

    const int threads = 256;
    const int blocks  = N_BATCH / threads;  // 256 blocks, one thread per row
    snn_fwd_kernel<<<blocks, threads, 0, stream>>>(x, beta, threshold, init_rand, out);
}

// Round 2
// 39.089 us; speedup vs baseline: 2.2922x; 2.2922x over previous
//
#include <hip/hip_runtime.h>
#include <math.h>

// SpikingNeuron forward scan, LDS-coalesced stores.
// x: (N, T) f32 row-major; beta, threshold: scalars; init_rand: (N,) f32.
// out = [spikes (N*T) | mems (N*T)] f32.
//
// Forward-value semantics (stop_gradient collapses):
//   fb   = sigmoid(beta)
//   m    = init_rand * thr                      (recorded as mems[:,0] pre-step)
//   m_new = fb*m + x[:,t]        (mul then add, NO fma -- must match numpy f32)
//   surplus = m_new - thr
//   spike = (surplus >= 0) ? 1 : 0
//   m     = spike ? surplus : m_new   (surplus == m_new - 1.0f*thr, one rounding)
//
// Structure: 1 wave (64 threads) per block, 64 rows per block, 1024 blocks
// (= 4 blocks/CU, LDS 33.3 KB/block -> 4 resident). Per 64-col chunk:
//   compute phase: thread t owns row t; reads x as float4 direct from global
//     (L1 absorbs the 1KB-stride pattern, FETCH already ideal), writes spike
//     and pre-step mem scalars into padded LDS tiles (stride 65 -> bank
//     (t+c)%32, 2-way max = free).
//   writeout phase: 16-lane groups store one row's contiguous 256B chunk as
//     float4 -> full 64B-line writes, WRITE_SIZE drops to ideal.

#define N_BATCH 65536
#define T_STEPS 256
#define ROWS    64          // rows per block == threads per block (1 wave)
#define CHUNK   64          // columns per chunk
#define NCHUNK  (T_STEPS / CHUNK)
#define STRIDE  (CHUNK + 1) // LDS pad: bank = (row + col) % 32

__global__ __launch_bounds__(64) void snn_fwd_kernel(
    const float* __restrict__ x,
    const float* __restrict__ beta_p,
    const float* __restrict__ thr_p,
    const float* __restrict__ init_rand,
    float* __restrict__ out)
{
#pragma clang fp contract(off)
    __shared__ float ss[ROWS * STRIDE];
    __shared__ float ms[ROWS * STRIDE];

    const int t   = threadIdx.x;          // 0..63
    const int row = blockIdx.x * ROWS + t;

    const float thr = thr_p[0];
    // Correctly-rounded f32 sigmoid via double intermediate.
    const float fb = (float)(1.0 / (1.0 + exp(-(double)beta_p[0])));

    float m = init_rand[row] * thr;

    const float4* __restrict__ xr =
        reinterpret_cast<const float4*>(x) + (size_t)row * (T_STEPS / 4);
    float* __restrict__ s_out = out;
    float* __restrict__ m_out = out + (size_t)N_BATCH * T_STEPS;

    for (int cc = 0; cc < NCHUNK; ++cc) {
        // ---- compute phase: row t, columns cc*CHUNK .. +63 ----
        float* __restrict__ srow = ss + t * STRIDE;
        float* __restrict__ mrow = ms + t * STRIDE;
#pragma unroll
        for (int i = 0; i < CHUNK / 4; ++i) {
            const float4 xv = xr[cc * (CHUNK / 4) + i];
            const float xe[4] = {xv.x, xv.y, xv.z, xv.w};
#pragma unroll
            for (int j = 0; j < 4; ++j) {
                mrow[4 * i + j] = m;              // pre-step memory
                float prod = fb * m;
                float mn   = prod + xe[j];
                float su   = mn - thr;
                srow[4 * i + j] = (su >= 0.0f) ? 1.0f : 0.0f;
                m = (su >= 0.0f) ? su : mn;
            }
        }
        __syncthreads();

        // ---- writeout phase: coalesced float4 stores ----
        const int k = t & 15;       // float4 index within row chunk
#pragma unroll
        for (int p = 0; p < 16; ++p) {
            const int rr = (t >> 4) + 4 * p;       // row within block
            const int la = rr * STRIDE + 4 * k;
            float4 sv, mv;
            sv.x = ss[la];     sv.y = ss[la + 1];
            sv.z = ss[la + 2]; sv.w = ss[la + 3];
            mv.x = ms[la];     mv.y = ms[la + 1];
            mv.z = ms[la + 2]; mv.w = ms[la + 3];
            const size_t g = (size_t)(blockIdx.x * ROWS + rr) * T_STEPS
                           + cc * CHUNK + 4 * k;
            *reinterpret_cast<float4*>(s_out + g) = sv;
            *reinterpret_cast<float4*>(m_out + g) = mv;
        }
        __syncthreads();
    }
}

extern "C" void kernel_launch(void* const* d_in, const int* in_sizes, int n_in,
                              void* d_out, int out_size, void* d_ws, size_t ws_size,
                              hipStream_t stream) {
    const float* x         = (const float*)d_in[0];
    const float* beta      = (const float*)d_in[1];
    const float* threshold = (const float*)d_in[2];
    const float* init_rand = (const float*)d_in[3];
    float* out             = (float*)d_out;

    const int threads = ROWS;                 // 64 = 1 wave
    const int blocks  = N_BATCH / ROWS;       // 1024 blocks
    snn_fwd_kernel<<<blocks, threads, 0, stream>>>(x, beta, threshold, init_rand, out);
}

// Round 4
// 36.183 us; speedup vs baseline: 2.4763x; 1.0803x over previous
//
#include <hip/hip_runtime.h>
#include <math.h>

// SpikingNeuron forward scan, LDS-coalesced stores + register x-prefetch +
// nontemporal output stores + wave-local sync (no vmcnt-draining barriers).
//
// Forward-value semantics (stop_gradient collapses):
//   fb   = sigmoid(beta)
//   m    = init_rand * thr                      (recorded as mems[:,0] pre-step)
//   m_new = fb*m + x[:,t]        (mul then add, NO fma -- must match numpy f32)
//   surplus = m_new - thr
//   spike = (surplus >= 0) ? 1 : 0
//   m     = spike ? surplus : m_new   (surplus == m_new - 1.0f*thr, one rounding)
//
// Structure: 1 wave (64 threads) per block, 64 rows per block, 1024 blocks
// (4 blocks/CU, LDS 33.3 KB -> 4 resident; occupancy is structurally capped
// at 4 waves/CU since the T-scan is serial per row -> all hiding is ILP).
// Since each block is a SINGLE wave, __syncthreads (which drains vmcnt(0),
// serializing global stores against the next chunk's compute) is replaced by
// s_waitcnt lgkmcnt(0) -- LDS ordering only, stores stay in flight.

#define N_BATCH 65536
#define T_STEPS 256
#define ROWS    64          // rows per block == threads per block (1 wave)
#define CHUNK   64          // columns per chunk
#define NCHUNK  (T_STEPS / CHUNK)
#define C4      (CHUNK / 4)
#define STRIDE  (CHUNK + 1) // LDS pad: bank = (row + col) % 32, 2-way = free

#define LDS_FENCE() asm volatile("s_waitcnt lgkmcnt(0)" ::: "memory")

// Native clang vector type: __builtin_nontemporal_store requires a real
// vector type, not HIP_vector_type<float,4>.
typedef float f32x4 __attribute__((ext_vector_type(4)));

__global__ __launch_bounds__(64) void snn_fwd_kernel(
    const float* __restrict__ x,
    const float* __restrict__ beta_p,
    const float* __restrict__ thr_p,
    const float* __restrict__ init_rand,
    float* __restrict__ out)
{
#pragma clang fp contract(off)
    __shared__ float ss[ROWS * STRIDE];
    __shared__ float ms[ROWS * STRIDE];

    const int t   = threadIdx.x;          // 0..63
    const int row = blockIdx.x * ROWS + t;

    const float thr = thr_p[0];
    // Correctly-rounded f32 sigmoid via double intermediate.
    const float fb = (float)(1.0 / (1.0 + exp(-(double)beta_p[0])));

    float m = init_rand[row] * thr;

    const f32x4* __restrict__ xr =
        reinterpret_cast<const f32x4*>(x) + (size_t)row * (T_STEPS / 4);
    float* __restrict__ s_out = out;
    float* __restrict__ m_out = out + (size_t)N_BATCH * T_STEPS;

    // Prefetch chunk 0 into registers.
    f32x4 xbuf[C4];
#pragma unroll
    for (int i = 0; i < C4; ++i) xbuf[i] = xr[i];

#pragma unroll
    for (int cc = 0; cc < NCHUNK; ++cc) {
        // Issue next chunk's loads now; latency hides under compute+writeout.
        f32x4 xnext[C4];
        if (cc + 1 < NCHUNK) {
#pragma unroll
            for (int i = 0; i < C4; ++i) xnext[i] = xr[(cc + 1) * C4 + i];
        }

        // ---- compute phase: row t, columns cc*CHUNK .. +63 ----
        float* __restrict__ srow = ss + t * STRIDE;
        float* __restrict__ mrow = ms + t * STRIDE;
#pragma unroll
        for (int i = 0; i < C4; ++i) {
            const f32x4 xv = xbuf[i];
#pragma unroll
            for (int j = 0; j < 4; ++j) {
                mrow[4 * i + j] = m;              // pre-step memory
                float prod = fb * m;
                float mn   = prod + xv[j];
                float su   = mn - thr;
                srow[4 * i + j] = (su >= 0.0f) ? 1.0f : 0.0f;
                m = (su >= 0.0f) ? su : mn;
            }
        }
        LDS_FENCE();   // single wave: LDS writes visible; no vmcnt drain

        // ---- writeout phase: coalesced nontemporal float4 stores ----
        const int k = t & 15;       // float4 index within row chunk
#pragma unroll
        for (int p = 0; p < 16; ++p) {
            const int rr = (t >> 4) + 4 * p;       // row within block
            const int la = rr * STRIDE + 4 * k;
            f32x4 sv, mv;
            sv.x = ss[la];     sv.y = ss[la + 1];
            sv.z = ss[la + 2]; sv.w = ss[la + 3];
            mv.x = ms[la];     mv.y = ms[la + 1];
            mv.z = ms[la + 2]; mv.w = ms[la + 3];
            const size_t g = (size_t)(blockIdx.x * ROWS + rr) * T_STEPS
                           + cc * CHUNK + 4 * k;
            __builtin_nontemporal_store(sv, reinterpret_cast<f32x4*>(s_out + g));
            __builtin_nontemporal_store(mv, reinterpret_cast<f32x4*>(m_out + g));
        }
        LDS_FENCE();   // LDS reads done before next chunk overwrites tiles

        if (cc + 1 < NCHUNK) {
#pragma unroll
            for (int i = 0; i < C4; ++i) xbuf[i] = xnext[i];
        }
    }
}

extern "C" void kernel_launch(void* const* d_in, const int* in_sizes, int n_in,
                              void* d_out, int out_size, void* d_ws, size_t ws_size,
                              hipStream_t stream) {
    const float* x         = (const float*)d_in[0];
    const float* beta      = (const float*)d_in[1];
    const float* threshold = (const float*)d_in[2];
    const float* init_rand = (const float*)d_in[3];
    float* out             = (float*)d_out;

    const int threads = ROWS;                 // 64 = 1 wave
    const int blocks  = N_BATCH / ROWS;       // 1024 blocks
    snn_fwd_kernel<<<blocks, threads, 0, stream>>>(x, beta, threshold, init_rand, out);
}

// Round 5
// 34.890 us; speedup vs baseline: 2.5681x; 1.0371x over previous
//
#include <hip/hip_runtime.h>
#include <math.h>

// SpikingNeuron forward scan — fully-coalesced R+W via LDS staging both ways.
//
// Forward-value semantics (stop_gradient collapses):
//   fb   = sigmoid(beta)
//   m    = init_rand * thr                      (recorded as mems[:,0] pre-step)
//   m_new = fb*m + x[:,t]        (mul then add, NO fma -- must match numpy f32)
//   surplus = m_new - thr
//   spike = (surplus >= 0) ? 1 : 0
//   m     = spike ? surplus : m_new   (surplus == m_new - 1.0f*thr, one rounding)
//
// Structure: 1 wave (64 threads) per block, 64 rows per block, 1024 blocks
// (exactly 4 blocks/CU co-resident; occupancy structurally capped — serial
// T-scan). All three streams now fully coalesced:
//   x:      cooperative loads (8-lane groups read contiguous 128B row-chunks,
//           16 lines/instr) -> regs -> padded LDS tile; scan reads column-wise
//           (bank (t+c)%32, 2-way = free). Replaces 64-lines/instr strided
//           loads that thrashed L1 (4 waves x 16KB > 32KB) and hogged L2 ports.
//   s/m:    scan writes scalars to padded LDS tiles; 8-lane groups write
//           contiguous float4 NT stores (full-line writes).
// CHUNK=32 so 3 tiles = 3*64*33*4B = 25.3KB -> 6 blocks/CU >= the 4 needed.
// Single-wave blocks: LDS ordering via s_waitcnt lgkmcnt(0), never vmcnt --
// NT stores and prefetch loads stay in flight across "barriers".

#define N_BATCH 65536
#define T_STEPS 256
#define ROWS    64          // rows per block == threads per block (1 wave)
#define CHUNK   32          // columns per chunk
#define NCHUNK  (T_STEPS / CHUNK)
#define STRIDE  (CHUNK + 1) // pad: bank = (row + col) % 32, 2-way = free
#define XPL     8           // float4s per lane per chunk (64*32/64/4)

#define LDS_FENCE() asm volatile("s_waitcnt lgkmcnt(0)" ::: "memory")

typedef float f32x4 __attribute__((ext_vector_type(4)));

__global__ __launch_bounds__(64) void snn_fwd_kernel(
    const float* __restrict__ x,
    const float* __restrict__ beta_p,
    const float* __restrict__ thr_p,
    const float* __restrict__ init_rand,
    float* __restrict__ out)
{
#pragma clang fp contract(off)
    __shared__ float xs[ROWS * STRIDE];
    __shared__ float ss[ROWS * STRIDE];
    __shared__ float ms[ROWS * STRIDE];

    const int t   = threadIdx.x;          // 0..63
    const int row = blockIdx.x * ROWS + t;

    const float thr = thr_p[0];
    // Correctly-rounded f32 sigmoid via double intermediate.
    const float fb = (float)(1.0 / (1.0 + exp(-(double)beta_p[0])));

    float m = init_rand[row] * thr;

    float* __restrict__ s_out = out;
    float* __restrict__ m_out = out + (size_t)N_BATCH * T_STEPS;

    // Cooperative-load geometry: 8-lane groups, lane t covers
    // row rr = (t>>3) + 8q, columns 4*(t&7) .. +3 of the chunk.
    const int k  = t & 7;        // float4 index within row-chunk (0..7)
    const int r0 = t >> 3;       // base row within 8-row group

    // ---- prologue: stage chunk 0 ----
    {
        f32x4 xld[XPL];
#pragma unroll
        for (int q = 0; q < XPL; ++q) {
            const int rr = r0 + 8 * q;
            xld[q] = *reinterpret_cast<const f32x4*>(
                x + (size_t)(blockIdx.x * ROWS + rr) * T_STEPS + 4 * k);
        }
#pragma unroll
        for (int q = 0; q < XPL; ++q) {
            const int rr = r0 + 8 * q;
            const int la = rr * STRIDE + 4 * k;
            xs[la]     = xld[q].x; xs[la + 1] = xld[q].y;
            xs[la + 2] = xld[q].z; xs[la + 3] = xld[q].w;
        }
        LDS_FENCE();
    }

#pragma unroll
    for (int cc = 0; cc < NCHUNK; ++cc) {
        // Issue next chunk's coalesced loads; latency hides under scan+writeout.
        f32x4 xnext[XPL];
        if (cc + 1 < NCHUNK) {
#pragma unroll
            for (int q = 0; q < XPL; ++q) {
                const int rr = r0 + 8 * q;
                xnext[q] = *reinterpret_cast<const f32x4*>(
                    x + (size_t)(blockIdx.x * ROWS + rr) * T_STEPS
                      + (cc + 1) * CHUNK + 4 * k);
            }
        }

        // ---- scan phase: lane t owns row t; x from LDS column reads ----
        float* __restrict__ xrow = xs + t * STRIDE;
        float* __restrict__ srow = ss + t * STRIDE;
        float* __restrict__ mrow = ms + t * STRIDE;
#pragma unroll
        for (int i = 0; i < CHUNK; ++i) {
            const float xv = xrow[i];
            mrow[i] = m;                      // pre-step memory
            float prod = fb * m;
            float mn   = prod + xv;
            float su   = mn - thr;
            srow[i] = (su >= 0.0f) ? 1.0f : 0.0f;
            m = (su >= 0.0f) ? su : mn;
        }
        LDS_FENCE();   // scan's LDS writes visible (and xs reads retired)

        // ---- writeout: coalesced nontemporal float4 stores ----
#pragma unroll
        for (int p = 0; p < 8; ++p) {
            const int rr = r0 + 8 * p;
            const int la = rr * STRIDE + 4 * k;
            f32x4 sv, mv;
            sv.x = ss[la];     sv.y = ss[la + 1];
            sv.z = ss[la + 2]; sv.w = ss[la + 3];
            mv.x = ms[la];     mv.y = ms[la + 1];
            mv.z = ms[la + 2]; mv.w = ms[la + 3];
            const size_t g = (size_t)(blockIdx.x * ROWS + rr) * T_STEPS
                           + cc * CHUNK + 4 * k;
            __builtin_nontemporal_store(sv, reinterpret_cast<f32x4*>(s_out + g));
            __builtin_nontemporal_store(mv, reinterpret_cast<f32x4*>(m_out + g));
        }
        LDS_FENCE();   // s/m reads done before next scan overwrites tiles

        // ---- stage next x chunk into LDS ----
        if (cc + 1 < NCHUNK) {
#pragma unroll
            for (int q = 0; q < XPL; ++q) {
                const int rr = r0 + 8 * q;
                const int la = rr * STRIDE + 4 * k;
                xs[la]     = xnext[q].x; xs[la + 1] = xnext[q].y;
                xs[la + 2] = xnext[q].z; xs[la + 3] = xnext[q].w;
            }
            LDS_FENCE();   // xs visible before next scan reads it
        }
    }
}

extern "C" void kernel_launch(void* const* d_in, const int* in_sizes, int n_in,
                              void* d_out, int out_size, void* d_ws, size_t ws_size,
                              hipStream_t stream) {
    const float* x         = (const float*)d_in[0];
    const float* beta      = (const float*)d_in[1];
    const float* threshold = (const float*)d_in[2];
    const float* init_rand = (const float*)d_in[3];
    float* out             = (float*)d_out;

    const int threads = ROWS;                 // 64 = 1 wave
    const int blocks  = N_BATCH / ROWS;       // 1024 blocks
    snn_fwd_kernel<<<blocks, threads, 0, stream>>>(x, beta, threshold, init_rand, out);
}